// Round 1
// baseline (3995.679 us; speedup 1.0000x reference)
//
#include <hip/hip_runtime.h>
#include <math.h>

// ============================ CSR build ============================

__global__ void k_hist(const int* __restrict__ dst, int* __restrict__ deg, int E){
    int i = blockIdx.x * blockDim.x + threadIdx.x;
    if (i < E) atomicAdd(&deg[dst[i]], 1);
}

__global__ void k_scan_sums(const int* __restrict__ deg, int* __restrict__ csum, int N){
    __shared__ int sd[256];
    int base = blockIdx.x * 1024;
    int s = 0;
    for (int i = threadIdx.x; i < 1024; i += 256){
        int idx = base + i;
        s += (idx < N) ? deg[idx] : 0;
    }
    sd[threadIdx.x] = s; __syncthreads();
    for (int off = 128; off > 0; off >>= 1){
        if (threadIdx.x < off) sd[threadIdx.x] += sd[threadIdx.x + off];
        __syncthreads();
    }
    if (threadIdx.x == 0) csum[blockIdx.x] = sd[0];
}

__global__ void k_scan_top(int* __restrict__ csum, int n){
    if (blockIdx.x == 0 && threadIdx.x == 0){
        int run = 0;
        for (int i = 0; i < n; ++i){ int v = csum[i]; csum[i] = run; run += v; }
    }
}

__global__ void k_scan_apply(const int* __restrict__ deg, const int* __restrict__ csum,
                             int* __restrict__ row_ptr, int N, int E){
    __shared__ int ts[256];
    int base = blockIdx.x * 1024 + threadIdx.x * 4;
    int v[4]; int s = 0;
    #pragma unroll
    for (int j = 0; j < 4; ++j){
        int idx = base + j;
        v[j] = (idx < N) ? deg[idx] : 0;
        s += v[j];
    }
    ts[threadIdx.x] = s; __syncthreads();
    #pragma unroll
    for (int off = 1; off < 256; off <<= 1){
        int t = (threadIdx.x >= off) ? ts[threadIdx.x - off] : 0;
        __syncthreads();
        ts[threadIdx.x] += t;
        __syncthreads();
    }
    int excl = ts[threadIdx.x] - s + csum[blockIdx.x];
    #pragma unroll
    for (int j = 0; j < 4; ++j){
        int idx = base + j;
        if (idx < N) row_ptr[idx] = excl;
        excl += v[j];
    }
    if (blockIdx.x == 0 && threadIdx.x == 0) row_ptr[N] = E;
}

__global__ void k_inv_deg(const int* __restrict__ deg, float* __restrict__ inv_deg, int N){
    int i = blockIdx.x * blockDim.x + threadIdx.x;
    if (i < N) inv_deg[i] = 1.0f / fmaxf((float)deg[i], 1.0f);
}

__global__ void k_fill(const int* __restrict__ src, const int* __restrict__ dst,
                       const int* __restrict__ row_ptr, int* __restrict__ cursor,
                       int* __restrict__ srcs, int E){
    int i = blockIdx.x * blockDim.x + threadIdx.x;
    if (i < E){
        int d = dst[i];
        int pos = row_ptr[d] + atomicAdd(&cursor[d], 1);
        srcs[pos] = src[i];
    }
}

// ============================ graph segment starts ============================
// batch is sorted ascending -> each graph occupies a contiguous row range.

__global__ void k_gstart_init(int* __restrict__ gstart, int N, int NG){
    int g = blockIdx.x * blockDim.x + threadIdx.x;
    if (g <= NG) gstart[g] = N;
}

__global__ void k_gstart_mark(const int* __restrict__ batch, int* __restrict__ gstart, int N){
    int i = blockIdx.x * blockDim.x + threadIdx.x;
    if (i < N){
        int b = batch[i];
        if (i == 0 || batch[i-1] != b) atomicMin(&gstart[b], i);
    }
}

__global__ void k_gstart_fix(int* __restrict__ gstart, int N, int NG){
    if (blockIdx.x == 0 && threadIdx.x == 0){
        for (int g = NG - 1; g >= 0; --g)
            if (gstart[g] == N) gstart[g] = gstart[g+1];
    }
}

// ============================ aggregation (mean over in-neighbors) ============================

// K = 11 (layer 1 input). One wave per dst node, lanes 0..10 hold one column each.
__global__ __launch_bounds__(256) void k_agg11(
    const float* __restrict__ x, const int* __restrict__ row_ptr,
    const int* __restrict__ srcs, const float* __restrict__ inv_deg,
    float* __restrict__ agg, int N)
{
    int node = blockIdx.x * 4 + (threadIdx.x >> 6);
    int lane = threadIdx.x & 63;
    if (node >= N) return;
    int beg = row_ptr[node], end = row_ptr[node+1];
    if (lane < 11){
        float s = 0.f;
        for (int e = beg; e < end; ++e){
            int sn = srcs[e];
            s += x[(size_t)sn * 11 + lane];
        }
        agg[(size_t)node * 11 + lane] = s * inv_deg[node];
    }
}

// K = 200. One wave per dst node; lanes 0..49 each hold a float4 (4 columns).
__global__ __launch_bounds__(256) void k_agg200(
    const float* __restrict__ h, const int* __restrict__ row_ptr,
    const int* __restrict__ srcs, const float* __restrict__ inv_deg,
    float* __restrict__ agg, int N)
{
    int node = blockIdx.x * 4 + (threadIdx.x >> 6);
    int lane = threadIdx.x & 63;
    if (node >= N) return;
    int beg = row_ptr[node], end = row_ptr[node+1];
    if (lane < 50){
        const float4* h4 = reinterpret_cast<const float4*>(h);
        float sx0=0.f, sy0=0.f, sz0=0.f, sw0=0.f;
        float sx1=0.f, sy1=0.f, sz1=0.f, sw1=0.f;
        int e = beg;
        for (; e + 1 < end; e += 2){
            int sa = srcs[e];
            int sb = srcs[e+1];
            float4 va = h4[(size_t)sa * 50 + lane];
            float4 vb = h4[(size_t)sb * 50 + lane];
            sx0 += va.x; sy0 += va.y; sz0 += va.z; sw0 += va.w;
            sx1 += vb.x; sy1 += vb.y; sz1 += vb.z; sw1 += vb.w;
        }
        if (e < end){
            int sa = srcs[e];
            float4 va = h4[(size_t)sa * 50 + lane];
            sx0 += va.x; sy0 += va.y; sz0 += va.z; sw0 += va.w;
        }
        float id = inv_deg[node];
        float4 o;
        o.x = (sx0 + sx1) * id;
        o.y = (sy0 + sy1) * id;
        o.z = (sz0 + sz1) * id;
        o.w = (sw0 + sw1) * id;
        reinterpret_cast<float4*>(agg)[(size_t)node * 50 + lane] = o;
    }
}

// ============================ layer 1 (K=11) ============================
// One block per row: out[m][c] = relu(sum_k agg[m][k]*Wl[c][k] + x[m][k]*Wr[c][k] + bl[c])
__global__ __launch_bounds__(256) void k_layer1(
    const float* __restrict__ x, const float* __restrict__ aggx,
    const float* __restrict__ Wl, const float* __restrict__ bl, const float* __restrict__ Wr,
    float* __restrict__ outp, int N)
{
    __shared__ float xr[11];
    __shared__ float ar[11];
    int m = blockIdx.x;
    if (threadIdx.x < 11){
        xr[threadIdx.x] = x[(size_t)m * 11 + threadIdx.x];
        ar[threadIdx.x] = aggx[(size_t)m * 11 + threadIdx.x];
    }
    __syncthreads();
    int c = threadIdx.x;
    if (c < 200){
        float s = bl[c];
        #pragma unroll
        for (int k = 0; k < 11; ++k){
            s = fmaf(ar[k], Wl[c * 11 + k], s);
            s = fmaf(xr[k], Wr[c * 11 + k], s);
        }
        outp[(size_t)m * 200 + c] = fmaxf(s, 0.f);
    }
}

// ============================ fused SAGE GEMM (layers 2..5) ============================
// out = relu(agg @ Wl^T + h @ Wr^T + bl), M x 200, K = 200 per phase.
// 64x64 tile, 4x4 micro-tile per thread, BK=8.
__global__ __launch_bounds__(256) void k_sage_gemm(
    const float* __restrict__ Aagg, const float* __restrict__ Ah,
    const float* __restrict__ Wl, const float* __restrict__ Wr,
    const float* __restrict__ bias, float* __restrict__ outp, int M)
{
    __shared__ __align__(16) float Al[8][68];
    __shared__ __align__(16) float Wt[8][68];
    const int bm = blockIdx.x * 64;
    const int bn = blockIdx.y * 64;
    const int tid = threadIdx.x;
    const int tx = tid & 15;
    const int ty = tid >> 4;
    const int kk = tid & 7;
    const int mm = tid >> 3;   // 0..31
    float acc[4][4] = {{0.f,0.f,0.f,0.f},{0.f,0.f,0.f,0.f},{0.f,0.f,0.f,0.f},{0.f,0.f,0.f,0.f}};

    for (int phase = 0; phase < 2; ++phase){
        const float* A = phase ? Ah : Aagg;
        const float* W = phase ? Wr : Wl;
        for (int k0 = 0; k0 < 200; k0 += 8){
            int gm  = bm + mm;
            int gm2 = gm + 32;
            Al[kk][mm]      = (gm  < M) ? A[(size_t)gm  * 200 + k0 + kk] : 0.f;
            Al[kk][mm + 32] = (gm2 < M) ? A[(size_t)gm2 * 200 + k0 + kk] : 0.f;
            int gc  = bn + mm;
            int gc2 = gc + 32;
            Wt[kk][mm]      = (gc  < 200) ? W[gc  * 200 + k0 + kk] : 0.f;
            Wt[kk][mm + 32] = (gc2 < 200) ? W[gc2 * 200 + k0 + kk] : 0.f;
            __syncthreads();
            #pragma unroll
            for (int k = 0; k < 8; ++k){
                const float4 av = *reinterpret_cast<const float4*>(&Al[k][ty * 4]);
                const float4 wv = *reinterpret_cast<const float4*>(&Wt[k][tx * 4]);
                acc[0][0] = fmaf(av.x, wv.x, acc[0][0]);
                acc[0][1] = fmaf(av.x, wv.y, acc[0][1]);
                acc[0][2] = fmaf(av.x, wv.z, acc[0][2]);
                acc[0][3] = fmaf(av.x, wv.w, acc[0][3]);
                acc[1][0] = fmaf(av.y, wv.x, acc[1][0]);
                acc[1][1] = fmaf(av.y, wv.y, acc[1][1]);
                acc[1][2] = fmaf(av.y, wv.z, acc[1][2]);
                acc[1][3] = fmaf(av.y, wv.w, acc[1][3]);
                acc[2][0] = fmaf(av.z, wv.x, acc[2][0]);
                acc[2][1] = fmaf(av.z, wv.y, acc[2][1]);
                acc[2][2] = fmaf(av.z, wv.z, acc[2][2]);
                acc[2][3] = fmaf(av.z, wv.w, acc[2][3]);
                acc[3][0] = fmaf(av.w, wv.x, acc[3][0]);
                acc[3][1] = fmaf(av.w, wv.y, acc[3][1]);
                acc[3][2] = fmaf(av.w, wv.z, acc[3][2]);
                acc[3][3] = fmaf(av.w, wv.w, acc[3][3]);
            }
            __syncthreads();
        }
    }
    const int c0 = bn + tx * 4;
    if (c0 < 200){
        const float4 bv = *reinterpret_cast<const float4*>(&bias[c0]);
        const int m0 = bm + ty * 4;
        #pragma unroll
        for (int i = 0; i < 4; ++i){
            int m = m0 + i;
            if (m < M){
                float4 o;
                o.x = fmaxf(acc[i][0] + bv.x, 0.f);
                o.y = fmaxf(acc[i][1] + bv.y, 0.f);
                o.z = fmaxf(acc[i][2] + bv.z, 0.f);
                o.w = fmaxf(acc[i][3] + bv.w, 0.f);
                *reinterpret_cast<float4*>(&outp[(size_t)m * 200 + c0]) = o;
            }
        }
    }
}

// ============================ pooling (contiguous segments) ============================

__global__ __launch_bounds__(256) void k_pool(
    const float* __restrict__ h, const int* __restrict__ gstart,
    float* __restrict__ gsum, int col_off)
{
    int g = blockIdx.x;
    int part = blockIdx.y;
    int beg = gstart[g], end = gstart[g+1];
    int len = end - beg;
    if (len <= 0) return;
    int chunk = (len + 7) / 8;
    int rb = beg + part * chunk;
    int re = rb + chunk; if (re > end) re = end;
    int c = threadIdx.x;
    if (c < 200 && rb < re){
        float s0 = 0.f, s1 = 0.f;
        int r = rb;
        for (; r + 1 < re; r += 2){
            s0 += h[(size_t)r * 200 + c];
            s1 += h[(size_t)(r+1) * 200 + c];
        }
        if (r < re) s0 += h[(size_t)r * 200 + c];
        atomicAdd(&gsum[(size_t)g * 1000 + col_off + c], s0 + s1);
    }
}

__global__ __launch_bounds__(256) void k_pool_finalize(
    float* __restrict__ gsum, const int* __restrict__ gstart, int NG)
{
    int g = blockIdx.x;
    int cnt = gstart[g+1] - gstart[g];
    float inv = 1.0f / fmaxf((float)cnt, 1.0f);
    for (int i = threadIdx.x; i < 1000; i += 256)
        gsum[(size_t)g * 1000 + i] *= inv;
}

// ============================ MLP head ============================

__global__ __launch_bounds__(256) void k_mlp(
    const float* __restrict__ in, const float* __restrict__ W,
    const float* __restrict__ b, float* __restrict__ outp, int Fin, int Fout)
{
    __shared__ __align__(16) float row[1000];
    int g = blockIdx.x;
    for (int i = threadIdx.x; i < Fin; i += 256) row[i] = in[(size_t)g * Fin + i];
    __syncthreads();
    int f4 = Fin >> 2;
    for (int c = threadIdx.x; c < Fout; c += 256){
        const float4* w4 = reinterpret_cast<const float4*>(W + (size_t)c * Fin);
        const float4* r4 = reinterpret_cast<const float4*>(row);
        float s = b[c];
        for (int k = 0; k < f4; ++k){
            float4 wv = w4[k]; float4 rv = r4[k];
            s = fmaf(wv.x, rv.x, s);
            s = fmaf(wv.y, rv.y, s);
            s = fmaf(wv.z, rv.z, s);
            s = fmaf(wv.w, rv.w, s);
        }
        outp[(size_t)g * Fout + c] = s;
    }
}

__global__ void k_mlp3(const float* __restrict__ in, const float* __restrict__ W,
                       const float* __restrict__ b, float* __restrict__ outp, int NG)
{
    int g = blockIdx.x * blockDim.x + threadIdx.x;
    if (g < NG){
        float s = b[0];
        const float* r = in + (size_t)g * 250;
        for (int k = 0; k < 250; ++k) s = fmaf(r[k], W[k], s);
        outp[g] = 1.0f / (1.0f + expf(-s));
    }
}

// ============================ launch ============================

extern "C" void kernel_launch(void* const* d_in, const int* in_sizes, int n_in,
                              void* d_out, int out_size, void* d_ws, size_t ws_size,
                              hipStream_t stream)
{
    const float* x    = (const float*)d_in[0];
    const int*   ei   = (const int*)d_in[1];
    const int*   batch= (const int*)d_in[2];
    const float* Wl[5]; const float* bl[5]; const float* Wr[5];
    for (int i = 0; i < 5; ++i){
        Wl[i] = (const float*)d_in[3 + 3*i];
        bl[i] = (const float*)d_in[4 + 3*i];
        Wr[i] = (const float*)d_in[5 + 3*i];
    }
    const float* pw1 = (const float*)d_in[18]; const float* pb1 = (const float*)d_in[19];
    const float* pw2 = (const float*)d_in[20]; const float* pb2 = (const float*)d_in[21];
    const float* pw3 = (const float*)d_in[22]; const float* pb3 = (const float*)d_in[23];
    float* out = (float*)d_out;

    const int N  = in_sizes[2];
    const int E  = in_sizes[1] / 2;
    const int NG = out_size;
    const int* esrc = ei;
    const int* edst = ei + E;

    // ---- workspace carve ----
    char* p = (char*)d_ws;
    auto carve = [&](size_t bytes)->void* {
        void* r = (void*)p;
        p += (bytes + 255) & ~(size_t)255;
        return r;
    };
    int*   deg     = (int*)  carve((size_t)N * 4);
    int*   cursor  = (int*)  carve((size_t)N * 4);
    int*   row_ptr = (int*)  carve(((size_t)N + 1) * 4);
    int*   csum    = (int*)  carve(4096);
    float* invdeg  = (float*)carve((size_t)N * 4);
    int*   gstart  = (int*)  carve(((size_t)NG + 1) * 4);
    int*   srcs    = (int*)  carve((size_t)E * 4);
    float* aggbuf  = (float*)carve((size_t)N * 200 * 4);
    float* hA      = (float*)carve((size_t)N * 200 * 4);
    float* hB      = (float*)carve((size_t)N * 200 * 4);
    float* gsum    = (float*)carve((size_t)NG * 1000 * 4);
    float* t1      = (float*)carve((size_t)NG * 500 * 4);
    float* t2      = (float*)carve((size_t)NG * 250 * 4);

    // ---- zero what must be zero ----
    hipMemsetAsync(deg,    0, (size_t)N * 4, stream);
    hipMemsetAsync(cursor, 0, (size_t)N * 4, stream);
    hipMemsetAsync(gsum,   0, (size_t)NG * 1000 * 4, stream);

    // ---- CSR build ----
    int eb = (E + 255) / 256;
    k_hist<<<eb, 256, 0, stream>>>(edst, deg, E);
    int nchunks = (N + 1023) / 1024;
    k_scan_sums<<<nchunks, 256, 0, stream>>>(deg, csum, N);
    k_scan_top<<<1, 64, 0, stream>>>(csum, nchunks);
    k_scan_apply<<<nchunks, 256, 0, stream>>>(deg, csum, row_ptr, N, E);
    k_inv_deg<<<(N + 255) / 256, 256, 0, stream>>>(deg, invdeg, N);
    k_fill<<<eb, 256, 0, stream>>>(esrc, edst, row_ptr, cursor, srcs, E);

    // ---- graph starts ----
    k_gstart_init<<<(NG + 256) / 256, 256, 0, stream>>>(gstart, N, NG);
    k_gstart_mark<<<(N + 255) / 256, 256, 0, stream>>>(batch, gstart, N);
    k_gstart_fix<<<1, 64, 0, stream>>>(gstart, N, NG);

    // ---- layer 1 ----
    int ab = (N + 3) / 4;
    k_agg11<<<ab, 256, 0, stream>>>(x, row_ptr, srcs, invdeg, aggbuf, N);
    k_layer1<<<N, 256, 0, stream>>>(x, aggbuf, Wl[0], bl[0], Wr[0], hA, N);
    k_pool<<<dim3(NG, 8), 256, 0, stream>>>(hA, gstart, gsum, 0);

    // ---- layers 2..5 ----
    float* hc = hA; float* hn = hB;
    for (int L = 1; L < 5; ++L){
        k_agg200<<<ab, 256, 0, stream>>>(hc, row_ptr, srcs, invdeg, aggbuf, N);
        k_sage_gemm<<<dim3((N + 63) / 64, 4), 256, 0, stream>>>(
            aggbuf, hc, Wl[L], Wr[L], bl[L], hn, N);
        k_pool<<<dim3(NG, 8), 256, 0, stream>>>(hn, gstart, gsum, 200 * L);
        float* t = hc; hc = hn; hn = t;
    }

    // ---- pool finalize + MLP head ----
    k_pool_finalize<<<NG, 256, 0, stream>>>(gsum, gstart, NG);
    k_mlp<<<NG, 256, 0, stream>>>(gsum, pw1, pb1, t1, 1000, 500);
    k_mlp<<<NG, 256, 0, stream>>>(t1, pw2, pb2, t2, 500, 250);
    k_mlp3<<<1, 256, 0, stream>>>(t2, pw3, pb3, out, NG);
}

// Round 2
// 2275.714 us; speedup vs baseline: 1.7558x; 1.7558x over previous
//
#include <hip/hip_runtime.h>
#include <math.h>

typedef __attribute__((ext_vector_type(8))) short bf16x8;
typedef __attribute__((ext_vector_type(4))) float floatx4;

#define ROWP 224          // padded row length (elements) for h/agg bf16 buffers
#define NT 14             // 14 x 16 = 224 output cols (200 real + pad)
#define KS 7              // 7 x 32 = 224 K (200 real + pad)
#define PACK_ELEMS (NT*KS*64*8)   // elements per packed weight matrix

__device__ __forceinline__ unsigned short f2bf(float f){
    union { float f; unsigned u; } v; v.f = f;
    unsigned r = v.u + 0x7FFF + ((v.u >> 16) & 1);
    return (unsigned short)(r >> 16);
}
__device__ __forceinline__ float bf2f(unsigned short u){
    union { unsigned u; float f; } v; v.u = ((unsigned)u) << 16;
    return v.f;
}

// ============================ CSR build ============================

__global__ void k_hist(const int* __restrict__ dst, int* __restrict__ deg, int E){
    int i = blockIdx.x * blockDim.x + threadIdx.x;
    if (i < E) atomicAdd(&deg[dst[i]], 1);
}

__global__ void k_scan_sums(const int* __restrict__ deg, int* __restrict__ csum, int N){
    __shared__ int sd[256];
    int base = blockIdx.x * 1024;
    int s = 0;
    for (int i = threadIdx.x; i < 1024; i += 256){
        int idx = base + i;
        s += (idx < N) ? deg[idx] : 0;
    }
    sd[threadIdx.x] = s; __syncthreads();
    for (int off = 128; off > 0; off >>= 1){
        if (threadIdx.x < off) sd[threadIdx.x] += sd[threadIdx.x + off];
        __syncthreads();
    }
    if (threadIdx.x == 0) csum[blockIdx.x] = sd[0];
}

__global__ void k_scan_top(int* __restrict__ csum, int n){
    if (blockIdx.x == 0 && threadIdx.x == 0){
        int run = 0;
        for (int i = 0; i < n; ++i){ int v = csum[i]; csum[i] = run; run += v; }
    }
}

__global__ void k_scan_apply(const int* __restrict__ deg, const int* __restrict__ csum,
                             int* __restrict__ row_ptr, int N, int E){
    __shared__ int ts[256];
    int base = blockIdx.x * 1024 + threadIdx.x * 4;
    int v[4]; int s = 0;
    #pragma unroll
    for (int j = 0; j < 4; ++j){
        int idx = base + j;
        v[j] = (idx < N) ? deg[idx] : 0;
        s += v[j];
    }
    ts[threadIdx.x] = s; __syncthreads();
    #pragma unroll
    for (int off = 1; off < 256; off <<= 1){
        int t = (threadIdx.x >= off) ? ts[threadIdx.x - off] : 0;
        __syncthreads();
        ts[threadIdx.x] += t;
        __syncthreads();
    }
    int excl = ts[threadIdx.x] - s + csum[blockIdx.x];
    #pragma unroll
    for (int j = 0; j < 4; ++j){
        int idx = base + j;
        if (idx < N) row_ptr[idx] = excl;
        excl += v[j];
    }
    if (blockIdx.x == 0 && threadIdx.x == 0) row_ptr[N] = E;
}

__global__ void k_inv_deg(const int* __restrict__ deg, float* __restrict__ inv_deg, int N){
    int i = blockIdx.x * blockDim.x + threadIdx.x;
    if (i < N) inv_deg[i] = 1.0f / fmaxf((float)deg[i], 1.0f);
}

__global__ void k_fill(const int* __restrict__ src, const int* __restrict__ dst,
                       const int* __restrict__ row_ptr, int* __restrict__ cursor,
                       int* __restrict__ srcs, int E){
    int i = blockIdx.x * blockDim.x + threadIdx.x;
    if (i < E){
        int d = dst[i];
        int pos = row_ptr[d] + atomicAdd(&cursor[d], 1);
        srcs[pos] = src[i];
    }
}

// ============================ graph segment starts ============================

__global__ void k_gstart_init(int* __restrict__ gstart, int N, int NG){
    int g = blockIdx.x * blockDim.x + threadIdx.x;
    if (g <= NG) gstart[g] = N;
}

__global__ void k_gstart_mark(const int* __restrict__ batch, int* __restrict__ gstart, int N){
    int i = blockIdx.x * blockDim.x + threadIdx.x;
    if (i < N){
        int b = batch[i];
        if (i == 0 || batch[i-1] != b) atomicMin(&gstart[b], i);
    }
}

__global__ void k_gstart_fix(int* __restrict__ gstart, int N, int NG){
    if (blockIdx.x == 0 && threadIdx.x == 0){
        for (int g = NG - 1; g >= 0; --g)
            if (gstart[g] == N) gstart[g] = gstart[g+1];
    }
}

// ============================ weight / bias packing ============================
// Pack W [200x200 fp32, row-major, W[n][k]] into MFMA B-fragment order:
// value(lane, j) = W[nt*16 + (lane&15)][ks*32 + (lane>>4)*8 + j], zero-padded.
__global__ void k_pack_w(const float* W0, const float* W1, const float* W2, const float* W3,
                         const float* W4, const float* W5, const float* W6, const float* W7,
                         unsigned short* __restrict__ out){
    const float* Ws[8] = {W0,W1,W2,W3,W4,W5,W6,W7};
    const float* W = Ws[blockIdx.z];
    int lane = threadIdx.x;
    int n  = blockIdx.x * 16 + (lane & 15);
    int k0 = blockIdx.y * 32 + (lane >> 4) * 8;
    unsigned short v[8];
    #pragma unroll
    for (int j = 0; j < 8; ++j){
        int k = k0 + j;
        float f = (n < 200 && k < 200) ? W[n * 200 + k] : 0.f;
        v[j] = f2bf(f);
    }
    uint4 u;
    u.x = (unsigned)v[0] | ((unsigned)v[1] << 16);
    u.y = (unsigned)v[2] | ((unsigned)v[3] << 16);
    u.z = (unsigned)v[4] | ((unsigned)v[5] << 16);
    u.w = (unsigned)v[6] | ((unsigned)v[7] << 16);
    size_t off = ((((size_t)blockIdx.z * NT + blockIdx.x) * KS + blockIdx.y) * 64 + lane) * 8;
    *reinterpret_cast<uint4*>(out + off) = u;
}

__global__ void k_pack_b(const float* b0, const float* b1, const float* b2, const float* b3,
                         float* __restrict__ out){
    const float* bs[4] = {b0,b1,b2,b3};
    int l = blockIdx.x, c = threadIdx.x;
    if (c < ROWP) out[l * ROWP + c] = (c < 200) ? bs[l][c] : 0.f;
}

// ============================ aggregation ============================

// K = 11 (layer-1 input), fp32. One wave per dst node.
__global__ __launch_bounds__(256) void k_agg11(
    const float* __restrict__ x, const int* __restrict__ row_ptr,
    const int* __restrict__ srcs, const float* __restrict__ inv_deg,
    float* __restrict__ agg, int N)
{
    int node = blockIdx.x * 4 + (threadIdx.x >> 6);
    int lane = threadIdx.x & 63;
    if (node >= N) return;
    int beg = row_ptr[node], end = row_ptr[node+1];
    if (lane < 11){
        float s = 0.f;
        for (int e = beg; e < end; ++e){
            int sn = srcs[e];
            s += x[(size_t)sn * 11 + lane];
        }
        agg[(size_t)node * 11 + lane] = s * inv_deg[node];
    }
}

// K = 200 bf16 rows (padded to ROWP). One wave per dst node; lanes 0..49 hold
// uint2 = 4 bf16 columns; lanes 50..55 zero the pad.
__global__ __launch_bounds__(256) void k_agg200(
    const unsigned short* __restrict__ h, const int* __restrict__ row_ptr,
    const int* __restrict__ srcs, const float* __restrict__ inv_deg,
    unsigned short* __restrict__ agg, int N)
{
    int node = blockIdx.x * 4 + (threadIdx.x >> 6);
    int lane = threadIdx.x & 63;
    if (node >= N) return;
    uint2* a2 = reinterpret_cast<uint2*>(agg);
    if (lane >= 50){
        if (lane < 56){ uint2 z; z.x = 0u; z.y = 0u; a2[(size_t)node * 56 + lane] = z; }
        return;
    }
    int beg = row_ptr[node], end = row_ptr[node+1];
    const uint2* h2 = reinterpret_cast<const uint2*>(h);
    float s0=0.f, s1=0.f, s2=0.f, s3=0.f;
    float t0=0.f, t1=0.f, t2=0.f, t3=0.f;
    int e = beg;
    for (; e + 1 < end; e += 2){
        int sa = srcs[e], sb = srcs[e+1];
        uint2 ua = h2[(size_t)sa * 56 + lane];
        uint2 ub = h2[(size_t)sb * 56 + lane];
        union { unsigned u; float f; } c;
        c.u = ua.x << 16;         s0 += c.f;
        c.u = ua.x & 0xffff0000u; s1 += c.f;
        c.u = ua.y << 16;         s2 += c.f;
        c.u = ua.y & 0xffff0000u; s3 += c.f;
        c.u = ub.x << 16;         t0 += c.f;
        c.u = ub.x & 0xffff0000u; t1 += c.f;
        c.u = ub.y << 16;         t2 += c.f;
        c.u = ub.y & 0xffff0000u; t3 += c.f;
    }
    if (e < end){
        int sa = srcs[e];
        uint2 ua = h2[(size_t)sa * 56 + lane];
        union { unsigned u; float f; } c;
        c.u = ua.x << 16;         s0 += c.f;
        c.u = ua.x & 0xffff0000u; s1 += c.f;
        c.u = ua.y << 16;         s2 += c.f;
        c.u = ua.y & 0xffff0000u; s3 += c.f;
    }
    float id = inv_deg[node];
    uint2 o;
    o.x = (unsigned)f2bf((s0 + t0) * id) | ((unsigned)f2bf((s1 + t1) * id) << 16);
    o.y = (unsigned)f2bf((s2 + t2) * id) | ((unsigned)f2bf((s3 + t3) * id) << 16);
    a2[(size_t)node * 56 + lane] = o;
}

// ============================ layer 1 (K=11, fp32 math, bf16 out) ============================

__global__ __launch_bounds__(256) void k_layer1(
    const float* __restrict__ x, const float* __restrict__ aggx,
    const float* __restrict__ Wl, const float* __restrict__ bl, const float* __restrict__ Wr,
    unsigned short* __restrict__ outp, int N)
{
    __shared__ float xr[11];
    __shared__ float ar[11];
    int m = blockIdx.x;
    if (threadIdx.x < 11){
        xr[threadIdx.x] = x[(size_t)m * 11 + threadIdx.x];
        ar[threadIdx.x] = aggx[(size_t)m * 11 + threadIdx.x];
    }
    __syncthreads();
    int c = threadIdx.x;
    if (c < 200){
        float s = bl[c];
        #pragma unroll
        for (int k = 0; k < 11; ++k){
            s = fmaf(ar[k], Wl[c * 11 + k], s);
            s = fmaf(xr[k], Wr[c * 11 + k], s);
        }
        outp[(size_t)m * ROWP + c] = f2bf(fmaxf(s, 0.f));
    } else if (c < ROWP){
        outp[(size_t)m * ROWP + c] = 0;
    }
}

// ============================ MFMA SAGE GEMM (layers 2..5) ============================
// out = relu(agg @ Wl^T + h @ Wr^T + bias); all bf16 in, fp32 accum, bf16 out.
// Block = 4 waves; wave w computes rows [bm + 16w, +16) x all 224 cols.
// A-frags straight from global (each element read once); B pre-packed frag-order (L2-hot).
__global__ __launch_bounds__(256) void k_sage_mfma(
    const unsigned short* __restrict__ Aagg, const unsigned short* __restrict__ Ah,
    const unsigned short* __restrict__ Wlp, const unsigned short* __restrict__ Wrp,
    const float* __restrict__ biasp, unsigned short* __restrict__ outp, int M)
{
    const int wave = threadIdx.x >> 6;
    const int lane = threadIdx.x & 63;
    const int n = lane & 15;
    const int q = lane >> 4;
    int row = blockIdx.x * 64 + wave * 16 + n;
    int rowc = row < M ? row : (M - 1);

    floatx4 acc[NT];
    #pragma unroll
    for (int nt = 0; nt < NT; ++nt) acc[nt] = (floatx4){0.f, 0.f, 0.f, 0.f};

    #pragma unroll
    for (int phase = 0; phase < 2; ++phase){
        const unsigned short* A = phase ? Ah : Aagg;
        const unsigned short* Wp = phase ? Wrp : Wlp;
        const unsigned short* arow = A + (size_t)rowc * ROWP + q * 8;
        #pragma unroll
        for (int ks = 0; ks < KS; ++ks){
            bf16x8 a = *reinterpret_cast<const bf16x8*>(arow + ks * 32);
            #pragma unroll
            for (int nt = 0; nt < NT; ++nt){
                bf16x8 b = *reinterpret_cast<const bf16x8*>(Wp + ((size_t)(nt * KS + ks) * 64 + lane) * 8);
                acc[nt] = __builtin_amdgcn_mfma_f32_16x16x32_bf16(a, b, acc[nt], 0, 0, 0);
            }
        }
    }

    // epilogue: C/D layout col=lane&15, row=(lane>>4)*4+reg
    int r0 = blockIdx.x * 64 + wave * 16 + q * 4;
    #pragma unroll
    for (int nt = 0; nt < NT; ++nt){
        float bsv = biasp[nt * 16 + n];
        #pragma unroll
        for (int r = 0; r < 4; ++r){
            int rr = r0 + r;
            if (rr < M){
                float v = fmaxf(acc[nt][r] + bsv, 0.f);
                outp[(size_t)rr * ROWP + nt * 16 + n] = f2bf(v);
            }
        }
    }
}

// ============================ pooling (contiguous segments, bf16 in) ============================

__global__ __launch_bounds__(256) void k_pool(
    const unsigned short* __restrict__ h, const int* __restrict__ gstart,
    float* __restrict__ gsum, int col_off)
{
    int g = blockIdx.x;
    int part = blockIdx.y;
    int beg = gstart[g], end = gstart[g+1];
    int len = end - beg;
    if (len <= 0) return;
    int chunk = (len + 7) / 8;
    int rb = beg + part * chunk;
    int re = rb + chunk; if (re > end) re = end;
    int c = threadIdx.x;
    if (c < 200 && rb < re){
        float s0 = 0.f, s1 = 0.f;
        int r = rb;
        for (; r + 1 < re; r += 2){
            s0 += bf2f(h[(size_t)r * ROWP + c]);
            s1 += bf2f(h[(size_t)(r+1) * ROWP + c]);
        }
        if (r < re) s0 += bf2f(h[(size_t)r * ROWP + c]);
        atomicAdd(&gsum[(size_t)g * 1000 + col_off + c], s0 + s1);
    }
}

__global__ __launch_bounds__(256) void k_pool_finalize(
    float* __restrict__ gsum, const int* __restrict__ gstart, int NG)
{
    int g = blockIdx.x;
    int cnt = gstart[g+1] - gstart[g];
    float inv = 1.0f / fmaxf((float)cnt, 1.0f);
    for (int i = threadIdx.x; i < 1000; i += 256)
        gsum[(size_t)g * 1000 + i] *= inv;
}

// ============================ MLP head (fp32) ============================

__global__ __launch_bounds__(256) void k_mlp(
    const float* __restrict__ in, const float* __restrict__ W,
    const float* __restrict__ b, float* __restrict__ outp, int Fin, int Fout)
{
    __shared__ __align__(16) float row[1000];
    int g = blockIdx.x;
    for (int i = threadIdx.x; i < Fin; i += 256) row[i] = in[(size_t)g * Fin + i];
    __syncthreads();
    int f4 = Fin >> 2;
    for (int c = threadIdx.x; c < Fout; c += 256){
        const float4* w4 = reinterpret_cast<const float4*>(W + (size_t)c * Fin);
        const float4* r4 = reinterpret_cast<const float4*>(row);
        float s = b[c];
        for (int k = 0; k < f4; ++k){
            float4 wv = w4[k]; float4 rv = r4[k];
            s = fmaf(wv.x, rv.x, s);
            s = fmaf(wv.y, rv.y, s);
            s = fmaf(wv.z, rv.z, s);
            s = fmaf(wv.w, rv.w, s);
        }
        outp[(size_t)g * Fout + c] = s;
    }
}

__global__ void k_mlp3(const float* __restrict__ in, const float* __restrict__ W,
                       const float* __restrict__ b, float* __restrict__ outp, int NG)
{
    int g = blockIdx.x * blockDim.x + threadIdx.x;
    if (g < NG){
        float s = b[0];
        const float* r = in + (size_t)g * 250;
        for (int k = 0; k < 250; ++k) s = fmaf(r[k], W[k], s);
        outp[g] = 1.0f / (1.0f + expf(-s));
    }
}

// ============================ launch ============================

extern "C" void kernel_launch(void* const* d_in, const int* in_sizes, int n_in,
                              void* d_out, int out_size, void* d_ws, size_t ws_size,
                              hipStream_t stream)
{
    const float* x    = (const float*)d_in[0];
    const int*   ei   = (const int*)d_in[1];
    const int*   batch= (const int*)d_in[2];
    const float* Wl[5]; const float* bl[5]; const float* Wr[5];
    for (int i = 0; i < 5; ++i){
        Wl[i] = (const float*)d_in[3 + 3*i];
        bl[i] = (const float*)d_in[4 + 3*i];
        Wr[i] = (const float*)d_in[5 + 3*i];
    }
    const float* pw1 = (const float*)d_in[18]; const float* pb1 = (const float*)d_in[19];
    const float* pw2 = (const float*)d_in[20]; const float* pb2 = (const float*)d_in[21];
    const float* pw3 = (const float*)d_in[22]; const float* pb3 = (const float*)d_in[23];
    float* out = (float*)d_out;

    const int N  = in_sizes[2];
    const int E  = in_sizes[1] / 2;
    const int NG = out_size;
    const int* esrc = ei;
    const int* edst = ei + E;

    // ---- workspace carve ----
    char* p = (char*)d_ws;
    auto carve = [&](size_t bytes)->void* {
        void* r = (void*)p;
        p += (bytes + 255) & ~(size_t)255;
        return r;
    };
    int*   deg     = (int*)  carve((size_t)N * 4);
    int*   cursor  = (int*)  carve((size_t)N * 4);
    int*   row_ptr = (int*)  carve(((size_t)N + 1) * 4);
    int*   csum    = (int*)  carve(4096);
    float* invdeg  = (float*)carve((size_t)N * 4);
    int*   gstart  = (int*)  carve(((size_t)NG + 1) * 4);
    int*   srcs    = (int*)  carve((size_t)E * 4);
    float* agg11   = (float*)carve((size_t)N * 11 * 4);
    unsigned short* agg16 = (unsigned short*)carve((size_t)N * ROWP * 2);
    unsigned short* hA16  = (unsigned short*)carve((size_t)N * ROWP * 2);
    unsigned short* hB16  = (unsigned short*)carve((size_t)N * ROWP * 2);
    unsigned short* wpack = (unsigned short*)carve((size_t)8 * PACK_ELEMS * 2);
    float* biasp   = (float*)carve((size_t)4 * ROWP * 4);
    float* gsum    = (float*)carve((size_t)NG * 1000 * 4);
    float* t1      = (float*)carve((size_t)NG * 500 * 4);
    float* t2      = (float*)carve((size_t)NG * 250 * 4);

    // ---- zero what must be zero ----
    hipMemsetAsync(deg,    0, (size_t)N * 4, stream);
    hipMemsetAsync(cursor, 0, (size_t)N * 4, stream);
    hipMemsetAsync(gsum,   0, (size_t)NG * 1000 * 4, stream);

    // ---- weight/bias packing (layers 2..5) ----
    k_pack_w<<<dim3(NT, KS, 8), 64, 0, stream>>>(
        Wl[1], Wr[1], Wl[2], Wr[2], Wl[3], Wr[3], Wl[4], Wr[4], wpack);
    k_pack_b<<<4, ROWP, 0, stream>>>(bl[1], bl[2], bl[3], bl[4], biasp);

    // ---- CSR build ----
    int eb = (E + 255) / 256;
    k_hist<<<eb, 256, 0, stream>>>(edst, deg, E);
    int nchunks = (N + 1023) / 1024;
    k_scan_sums<<<nchunks, 256, 0, stream>>>(deg, csum, N);
    k_scan_top<<<1, 64, 0, stream>>>(csum, nchunks);
    k_scan_apply<<<nchunks, 256, 0, stream>>>(deg, csum, row_ptr, N, E);
    k_inv_deg<<<(N + 255) / 256, 256, 0, stream>>>(deg, invdeg, N);
    k_fill<<<eb, 256, 0, stream>>>(esrc, edst, row_ptr, cursor, srcs, E);

    // ---- graph starts ----
    k_gstart_init<<<(NG + 256) / 256, 256, 0, stream>>>(gstart, N, NG);
    k_gstart_mark<<<(N + 255) / 256, 256, 0, stream>>>(batch, gstart, N);
    k_gstart_fix<<<1, 64, 0, stream>>>(gstart, N, NG);

    // ---- layer 1 (fp32 math, bf16 out) ----
    int ab = (N + 3) / 4;
    k_agg11<<<ab, 256, 0, stream>>>(x, row_ptr, srcs, invdeg, agg11, N);
    k_layer1<<<N, 256, 0, stream>>>(x, agg11, Wl[0], bl[0], Wr[0], hA16, N);
    k_pool<<<dim3(NG, 8), 256, 0, stream>>>(hA16, gstart, gsum, 0);

    // ---- layers 2..5 (bf16 MFMA) ----
    unsigned short* hc = hA16; unsigned short* hn = hB16;
    int gb = (N + 63) / 64;
    for (int L = 1; L < 5; ++L){
        k_agg200<<<ab, 256, 0, stream>>>(hc, row_ptr, srcs, invdeg, agg16, N);
        const unsigned short* Wlp = wpack + (size_t)((L-1)*2 + 0) * PACK_ELEMS;
        const unsigned short* Wrp = wpack + (size_t)((L-1)*2 + 1) * PACK_ELEMS;
        k_sage_mfma<<<gb, 256, 0, stream>>>(agg16, hc, Wlp, Wrp,
                                            biasp + (L-1) * ROWP, hn, N);
        k_pool<<<dim3(NG, 8), 256, 0, stream>>>(hn, gstart, gsum, 200 * L);
        unsigned short* t = hc; hc = hn; hn = t;
    }

    // ---- pool finalize + MLP head ----
    k_pool_finalize<<<NG, 256, 0, stream>>>(gsum, gstart, NG);
    k_mlp<<<NG, 256, 0, stream>>>(gsum, pw1, pb1, t1, 1000, 500);
    k_mlp<<<NG, 256, 0, stream>>>(t1, pw2, pb2, t2, 500, 250);
    k_mlp3<<<1, 256, 0, stream>>>(t2, pw3, pb3, out, NG);
}

// Round 3
// 1957.357 us; speedup vs baseline: 2.0414x; 1.1626x over previous
//
#include <hip/hip_runtime.h>
#include <math.h>

typedef __attribute__((ext_vector_type(8))) short bf16x8;
typedef __attribute__((ext_vector_type(4))) float floatx4;
typedef __attribute__((ext_vector_type(2))) float floatx2;

#define ROWP 224          // padded row length (elements) for h/agg bf16 buffers
#define NT 14             // 14 x 16 = 224 output cols (200 real + pad)
#define KS 7              // 7 x 32 = 224 K (200 real + pad)
#define PACK_ELEMS (NT*KS*64*8)   // elements per packed weight matrix

__device__ __forceinline__ unsigned short f2bf(float f){
    union { float f; unsigned u; } v; v.f = f;
    unsigned r = v.u + 0x7FFF + ((v.u >> 16) & 1);
    return (unsigned short)(r >> 16);
}
__device__ __forceinline__ float bf2f(unsigned short u){
    union { unsigned u; float f; } v; v.u = ((unsigned)u) << 16;
    return v.f;
}

// ============================ CSR build ============================

__global__ void k_hist(const int* __restrict__ dst, int* __restrict__ deg, int E){
    int i = blockIdx.x * blockDim.x + threadIdx.x;
    if (i < E) atomicAdd(&deg[dst[i]], 1);
}

__global__ void k_scan_sums(const int* __restrict__ deg, int* __restrict__ csum, int N){
    __shared__ int sd[256];
    int base = blockIdx.x * 1024;
    int s = 0;
    for (int i = threadIdx.x; i < 1024; i += 256){
        int idx = base + i;
        s += (idx < N) ? deg[idx] : 0;
    }
    sd[threadIdx.x] = s; __syncthreads();
    for (int off = 128; off > 0; off >>= 1){
        if (threadIdx.x < off) sd[threadIdx.x] += sd[threadIdx.x + off];
        __syncthreads();
    }
    if (threadIdx.x == 0) csum[blockIdx.x] = sd[0];
}

__global__ void k_scan_top(int* __restrict__ csum, int n){
    if (blockIdx.x == 0 && threadIdx.x == 0){
        int run = 0;
        for (int i = 0; i < n; ++i){ int v = csum[i]; csum[i] = run; run += v; }
    }
}

__global__ void k_scan_apply(const int* __restrict__ deg, const int* __restrict__ csum,
                             int* __restrict__ row_ptr, int N, int E){
    __shared__ int ts[256];
    int base = blockIdx.x * 1024 + threadIdx.x * 4;
    int v[4]; int s = 0;
    #pragma unroll
    for (int j = 0; j < 4; ++j){
        int idx = base + j;
        v[j] = (idx < N) ? deg[idx] : 0;
        s += v[j];
    }
    ts[threadIdx.x] = s; __syncthreads();
    #pragma unroll
    for (int off = 1; off < 256; off <<= 1){
        int t = (threadIdx.x >= off) ? ts[threadIdx.x - off] : 0;
        __syncthreads();
        ts[threadIdx.x] += t;
        __syncthreads();
    }
    int excl = ts[threadIdx.x] - s + csum[blockIdx.x];
    #pragma unroll
    for (int j = 0; j < 4; ++j){
        int idx = base + j;
        if (idx < N) row_ptr[idx] = excl;
        excl += v[j];
    }
    if (blockIdx.x == 0 && threadIdx.x == 0) row_ptr[N] = E;
}

__global__ void k_inv_deg(const int* __restrict__ deg, float* __restrict__ inv_deg, int N){
    int i = blockIdx.x * blockDim.x + threadIdx.x;
    if (i < N) inv_deg[i] = 1.0f / fmaxf((float)deg[i], 1.0f);
}

__global__ void k_fill(const int* __restrict__ src, const int* __restrict__ dst,
                       const int* __restrict__ row_ptr, int* __restrict__ cursor,
                       int* __restrict__ srcs, int E){
    int i = blockIdx.x * blockDim.x + threadIdx.x;
    if (i < E){
        int d = dst[i];
        int pos = row_ptr[d] + atomicAdd(&cursor[d], 1);
        srcs[pos] = src[i];
    }
}

// ============================ graph segment starts ============================

__global__ void k_gstart_init(int* __restrict__ gstart, int N, int NG){
    int g = blockIdx.x * blockDim.x + threadIdx.x;
    if (g <= NG) gstart[g] = N;
}

__global__ void k_gstart_mark(const int* __restrict__ batch, int* __restrict__ gstart, int N){
    int i = blockIdx.x * blockDim.x + threadIdx.x;
    if (i < N){
        int b = batch[i];
        if (i == 0 || batch[i-1] != b) atomicMin(&gstart[b], i);
    }
}

__global__ void k_gstart_fix(int* __restrict__ gstart, int N, int NG){
    if (blockIdx.x == 0 && threadIdx.x == 0){
        for (int g = NG - 1; g >= 0; --g)
            if (gstart[g] == N) gstart[g] = gstart[g+1];
    }
}

// ============================ weight / bias packing ============================
// Pack W [200x200 fp32, row-major, W[n][k]] into MFMA B-fragment order:
// value(lane, j) = W[nt*16 + (lane&15)][ks*32 + (lane>>4)*8 + j], zero-padded.
__global__ void k_pack_w(const float* W0, const float* W1, const float* W2, const float* W3,
                         const float* W4, const float* W5, const float* W6, const float* W7,
                         unsigned short* __restrict__ out){
    const float* Ws[8] = {W0,W1,W2,W3,W4,W5,W6,W7};
    const float* W = Ws[blockIdx.z];
    int lane = threadIdx.x;
    int n  = blockIdx.x * 16 + (lane & 15);
    int k0 = blockIdx.y * 32 + (lane >> 4) * 8;
    unsigned short v[8];
    #pragma unroll
    for (int j = 0; j < 8; ++j){
        int k = k0 + j;
        float f = (n < 200 && k < 200) ? W[n * 200 + k] : 0.f;
        v[j] = f2bf(f);
    }
    uint4 u;
    u.x = (unsigned)v[0] | ((unsigned)v[1] << 16);
    u.y = (unsigned)v[2] | ((unsigned)v[3] << 16);
    u.z = (unsigned)v[4] | ((unsigned)v[5] << 16);
    u.w = (unsigned)v[6] | ((unsigned)v[7] << 16);
    size_t off = ((((size_t)blockIdx.z * NT + blockIdx.x) * KS + blockIdx.y) * 64 + lane) * 8;
    *reinterpret_cast<uint4*>(out + off) = u;
}

__global__ void k_pack_b(const float* b0, const float* b1, const float* b2, const float* b3,
                         float* __restrict__ out){
    const float* bs[4] = {b0,b1,b2,b3};
    int l = blockIdx.x, c = threadIdx.x;
    if (c < ROWP) out[l * ROWP + c] = (c < 200) ? bs[l][c] : 0.f;
}

// ============================ aggregation ============================

// K = 11 (layer-1 input), fp32. One wave per dst node.
__global__ __launch_bounds__(256) void k_agg11(
    const float* __restrict__ x, const int* __restrict__ row_ptr,
    const int* __restrict__ srcs, const float* __restrict__ inv_deg,
    float* __restrict__ agg, int N)
{
    int node = blockIdx.x * 4 + (threadIdx.x >> 6);
    int lane = threadIdx.x & 63;
    if (node >= N) return;
    int beg = row_ptr[node], end = row_ptr[node+1];
    if (lane < 11){
        float s = 0.f;
        for (int e = beg; e < end; ++e){
            int sn = srcs[e];
            s += x[(size_t)sn * 11 + lane];
        }
        agg[(size_t)node * 11 + lane] = s * inv_deg[node];
    }
}

// fp8 gather-aggregate. One wave per dst node. Row = 224 fp8 bytes = 14 uint4.
// Wave splits into 4 groups of 14 lanes; group g handles edges beg+g, beg+g+4, ...
// (2-deep unroll -> up to 8 x 16 B loads in flight). Cross-group combine via shfl_xor.
__device__ __forceinline__ void accum_fp8(float* acc, uint4 u){
    floatx2 f;
    f = __builtin_amdgcn_cvt_pk_f32_fp8((int)u.x, false); acc[0] += f[0];  acc[1] += f[1];
    f = __builtin_amdgcn_cvt_pk_f32_fp8((int)u.x, true ); acc[2] += f[0];  acc[3] += f[1];
    f = __builtin_amdgcn_cvt_pk_f32_fp8((int)u.y, false); acc[4] += f[0];  acc[5] += f[1];
    f = __builtin_amdgcn_cvt_pk_f32_fp8((int)u.y, true ); acc[6] += f[0];  acc[7] += f[1];
    f = __builtin_amdgcn_cvt_pk_f32_fp8((int)u.z, false); acc[8] += f[0];  acc[9] += f[1];
    f = __builtin_amdgcn_cvt_pk_f32_fp8((int)u.z, true ); acc[10] += f[0]; acc[11] += f[1];
    f = __builtin_amdgcn_cvt_pk_f32_fp8((int)u.w, false); acc[12] += f[0]; acc[13] += f[1];
    f = __builtin_amdgcn_cvt_pk_f32_fp8((int)u.w, true ); acc[14] += f[0]; acc[15] += f[1];
}

__global__ __launch_bounds__(256) void k_agg200(
    const unsigned char* __restrict__ h8, const int* __restrict__ row_ptr,
    const int* __restrict__ srcs, const float* __restrict__ inv_deg,
    unsigned short* __restrict__ agg, int N)
{
    int node = blockIdx.x * 4 + (threadIdx.x >> 6);
    int lane = threadIdx.x & 63;
    if (node >= N) return;
    int g = lane >> 4;    // group 0..3
    int l = lane & 15;    // lane-in-group; active if l < 14
    int beg = row_ptr[node], end = row_ptr[node + 1];

    float acc[16];
    #pragma unroll
    for (int i = 0; i < 16; ++i) acc[i] = 0.f;

    if (l < 14){
        const uint4* h4 = reinterpret_cast<const uint4*>(h8);
        int e = beg + g;
        for (; e + 4 < end; e += 8){
            int sa = srcs[e];
            int sb = srcs[e + 4];
            uint4 ua = h4[(size_t)sa * 14 + l];
            uint4 ub = h4[(size_t)sb * 14 + l];
            accum_fp8(acc, ua);
            accum_fp8(acc, ub);
        }
        if (e < end){
            int sa = srcs[e];
            uint4 ua = h4[(size_t)sa * 14 + l];
            accum_fp8(acc, ua);
        }
    }

    // combine the 4 groups (lanes at xor-offsets 16 and 32)
    #pragma unroll
    for (int i = 0; i < 16; ++i){
        acc[i] += __shfl_xor(acc[i], 32, 64);
        acc[i] += __shfl_xor(acc[i], 16, 64);
    }

    if (g == 0 && l < 14){
        float id = inv_deg[node];
        unsigned d[8];
        #pragma unroll
        for (int i = 0; i < 8; ++i){
            d[i] = (unsigned)f2bf(acc[2*i] * id) | ((unsigned)f2bf(acc[2*i+1] * id) << 16);
        }
        uint4* a4 = reinterpret_cast<uint4*>(agg);
        size_t base = (size_t)node * 28 + (size_t)l * 2;  // 224 bf16 = 28 uint4/row
        uint4 o0; o0.x = d[0]; o0.y = d[1]; o0.z = d[2]; o0.w = d[3];
        uint4 o1; o1.x = d[4]; o1.y = d[5]; o1.z = d[6]; o1.w = d[7];
        a4[base] = o0;
        a4[base + 1] = o1;
    }
}

// ============================ layer 1 (K=11, fp32 math, bf16 out) ============================

__global__ __launch_bounds__(256) void k_layer1(
    const float* __restrict__ x, const float* __restrict__ aggx,
    const float* __restrict__ Wl, const float* __restrict__ bl, const float* __restrict__ Wr,
    unsigned short* __restrict__ outp, int N)
{
    __shared__ float xr[11];
    __shared__ float ar[11];
    int m = blockIdx.x;
    if (threadIdx.x < 11){
        xr[threadIdx.x] = x[(size_t)m * 11 + threadIdx.x];
        ar[threadIdx.x] = aggx[(size_t)m * 11 + threadIdx.x];
    }
    __syncthreads();
    int c = threadIdx.x;
    if (c < 200){
        float s = bl[c];
        #pragma unroll
        for (int k = 0; k < 11; ++k){
            s = fmaf(ar[k], Wl[c * 11 + k], s);
            s = fmaf(xr[k], Wr[c * 11 + k], s);
        }
        outp[(size_t)m * ROWP + c] = f2bf(fmaxf(s, 0.f));
    } else if (c < ROWP){
        outp[(size_t)m * ROWP + c] = 0;
    }
}

// ============================ MFMA SAGE GEMM (layers 2..5) ============================

__global__ __launch_bounds__(256) void k_sage_mfma(
    const unsigned short* __restrict__ Aagg, const unsigned short* __restrict__ Ah,
    const unsigned short* __restrict__ Wlp, const unsigned short* __restrict__ Wrp,
    const float* __restrict__ biasp, unsigned short* __restrict__ outp, int M)
{
    const int wave = threadIdx.x >> 6;
    const int lane = threadIdx.x & 63;
    const int n = lane & 15;
    const int q = lane >> 4;
    int row = blockIdx.x * 64 + wave * 16 + n;
    int rowc = row < M ? row : (M - 1);

    floatx4 acc[NT];
    #pragma unroll
    for (int nt = 0; nt < NT; ++nt) acc[nt] = (floatx4){0.f, 0.f, 0.f, 0.f};

    #pragma unroll
    for (int phase = 0; phase < 2; ++phase){
        const unsigned short* A = phase ? Ah : Aagg;
        const unsigned short* Wp = phase ? Wrp : Wlp;
        const unsigned short* arow = A + (size_t)rowc * ROWP + q * 8;
        #pragma unroll
        for (int ks = 0; ks < KS; ++ks){
            bf16x8 a = *reinterpret_cast<const bf16x8*>(arow + ks * 32);
            #pragma unroll
            for (int nt = 0; nt < NT; ++nt){
                bf16x8 b = *reinterpret_cast<const bf16x8*>(Wp + ((size_t)(nt * KS + ks) * 64 + lane) * 8);
                acc[nt] = __builtin_amdgcn_mfma_f32_16x16x32_bf16(a, b, acc[nt], 0, 0, 0);
            }
        }
    }

    // epilogue: C/D layout col=lane&15, row=(lane>>4)*4+reg
    int r0 = blockIdx.x * 64 + wave * 16 + q * 4;
    #pragma unroll
    for (int nt = 0; nt < NT; ++nt){
        float bsv = biasp[nt * 16 + n];
        #pragma unroll
        for (int r = 0; r < 4; ++r){
            int rr = r0 + r;
            if (rr < M){
                float v = fmaxf(acc[nt][r] + bsv, 0.f);
                outp[(size_t)rr * ROWP + nt * 16 + n] = f2bf(v);
            }
        }
    }
}

// ============================ pooling + fp8 shadow write ============================
// Every node row belongs to exactly one graph segment, so each h element is
// visited exactly once across the (g, part) grid -> fp8 shadow h8 is complete.

__global__ __launch_bounds__(256) void k_pool(
    const unsigned short* __restrict__ h, const int* __restrict__ gstart,
    float* __restrict__ gsum, int col_off, unsigned char* __restrict__ h8)
{
    int g = blockIdx.x;
    int part = blockIdx.y;
    int beg = gstart[g], end = gstart[g+1];
    int len = end - beg;
    if (len <= 0) return;
    int chunk = (len + 7) / 8;
    int rb = beg + part * chunk;
    int re = rb + chunk; if (re > end) re = end;
    int c = threadIdx.x;
    if (c < ROWP && rb < re){
        float s = 0.f;
        for (int r = rb; r < re; ++r){
            float v = (c < 200) ? bf2f(h[(size_t)r * ROWP + c]) : 0.f;
            s += v;
            int pk = __builtin_amdgcn_cvt_pk_fp8_f32(v, v, 0, false);
            h8[(size_t)r * ROWP + c] = (unsigned char)(pk & 0xFF);
        }
        if (c < 200) atomicAdd(&gsum[(size_t)g * 1000 + col_off + c], s);
    }
}

__global__ __launch_bounds__(256) void k_pool_finalize(
    float* __restrict__ gsum, const int* __restrict__ gstart, int NG)
{
    int g = blockIdx.x;
    int cnt = gstart[g+1] - gstart[g];
    float inv = 1.0f / fmaxf((float)cnt, 1.0f);
    for (int i = threadIdx.x; i < 1000; i += 256)
        gsum[(size_t)g * 1000 + i] *= inv;
}

// ============================ MLP head (fp32) ============================

__global__ __launch_bounds__(256) void k_mlp(
    const float* __restrict__ in, const float* __restrict__ W,
    const float* __restrict__ b, float* __restrict__ outp, int Fin, int Fout)
{
    __shared__ __align__(16) float row[1000];
    int g = blockIdx.x;
    for (int i = threadIdx.x; i < Fin; i += 256) row[i] = in[(size_t)g * Fin + i];
    __syncthreads();
    int f4 = Fin >> 2;
    for (int c = threadIdx.x; c < Fout; c += 256){
        const float4* w4 = reinterpret_cast<const float4*>(W + (size_t)c * Fin);
        const float4* r4 = reinterpret_cast<const float4*>(row);
        float s = b[c];
        for (int k = 0; k < f4; ++k){
            float4 wv = w4[k]; float4 rv = r4[k];
            s = fmaf(wv.x, rv.x, s);
            s = fmaf(wv.y, rv.y, s);
            s = fmaf(wv.z, rv.z, s);
            s = fmaf(wv.w, rv.w, s);
        }
        outp[(size_t)g * Fout + c] = s;
    }
}

__global__ void k_mlp3(const float* __restrict__ in, const float* __restrict__ W,
                       const float* __restrict__ b, float* __restrict__ outp, int NG)
{
    int g = blockIdx.x * blockDim.x + threadIdx.x;
    if (g < NG){
        float s = b[0];
        const float* r = in + (size_t)g * 250;
        for (int k = 0; k < 250; ++k) s = fmaf(r[k], W[k], s);
        outp[g] = 1.0f / (1.0f + expf(-s));
    }
}

// ============================ launch ============================

extern "C" void kernel_launch(void* const* d_in, const int* in_sizes, int n_in,
                              void* d_out, int out_size, void* d_ws, size_t ws_size,
                              hipStream_t stream)
{
    const float* x    = (const float*)d_in[0];
    const int*   ei   = (const int*)d_in[1];
    const int*   batch= (const int*)d_in[2];
    const float* Wl[5]; const float* bl[5]; const float* Wr[5];
    for (int i = 0; i < 5; ++i){
        Wl[i] = (const float*)d_in[3 + 3*i];
        bl[i] = (const float*)d_in[4 + 3*i];
        Wr[i] = (const float*)d_in[5 + 3*i];
    }
    const float* pw1 = (const float*)d_in[18]; const float* pb1 = (const float*)d_in[19];
    const float* pw2 = (const float*)d_in[20]; const float* pb2 = (const float*)d_in[21];
    const float* pw3 = (const float*)d_in[22]; const float* pb3 = (const float*)d_in[23];
    float* out = (float*)d_out;

    const int N  = in_sizes[2];
    const int E  = in_sizes[1] / 2;
    const int NG = out_size;
    const int* esrc = ei;
    const int* edst = ei + E;

    // ---- workspace carve ----
    char* p = (char*)d_ws;
    auto carve = [&](size_t bytes)->void* {
        void* r = (void*)p;
        p += (bytes + 255) & ~(size_t)255;
        return r;
    };
    int*   deg     = (int*)  carve((size_t)N * 4);
    int*   cursor  = (int*)  carve((size_t)N * 4);
    int*   row_ptr = (int*)  carve(((size_t)N + 1) * 4);
    int*   csum    = (int*)  carve(4096);
    float* invdeg  = (float*)carve((size_t)N * 4);
    int*   gstart  = (int*)  carve(((size_t)NG + 1) * 4);
    int*   srcs    = (int*)  carve((size_t)E * 4);
    float* agg11   = (float*)carve((size_t)N * 11 * 4);
    unsigned short* agg16 = (unsigned short*)carve((size_t)N * ROWP * 2);
    unsigned short* hA16  = (unsigned short*)carve((size_t)N * ROWP * 2);
    unsigned short* hB16  = (unsigned short*)carve((size_t)N * ROWP * 2);
    unsigned char*  h8A   = (unsigned char*) carve((size_t)N * ROWP);
    unsigned char*  h8B   = (unsigned char*) carve((size_t)N * ROWP);
    unsigned short* wpack = (unsigned short*)carve((size_t)8 * PACK_ELEMS * 2);
    float* biasp   = (float*)carve((size_t)4 * ROWP * 4);
    float* gsum    = (float*)carve((size_t)NG * 1000 * 4);
    float* t1      = (float*)carve((size_t)NG * 500 * 4);
    float* t2      = (float*)carve((size_t)NG * 250 * 4);

    // ---- zero what must be zero ----
    hipMemsetAsync(deg,    0, (size_t)N * 4, stream);
    hipMemsetAsync(cursor, 0, (size_t)N * 4, stream);
    hipMemsetAsync(gsum,   0, (size_t)NG * 1000 * 4, stream);

    // ---- weight/bias packing (layers 2..5) ----
    k_pack_w<<<dim3(NT, KS, 8), 64, 0, stream>>>(
        Wl[1], Wr[1], Wl[2], Wr[2], Wl[3], Wr[3], Wl[4], Wr[4], wpack);
    k_pack_b<<<4, ROWP, 0, stream>>>(bl[1], bl[2], bl[3], bl[4], biasp);

    // ---- CSR build ----
    int eb = (E + 255) / 256;
    k_hist<<<eb, 256, 0, stream>>>(edst, deg, E);
    int nchunks = (N + 1023) / 1024;
    k_scan_sums<<<nchunks, 256, 0, stream>>>(deg, csum, N);
    k_scan_top<<<1, 64, 0, stream>>>(csum, nchunks);
    k_scan_apply<<<nchunks, 256, 0, stream>>>(deg, csum, row_ptr, N, E);
    k_inv_deg<<<(N + 255) / 256, 256, 0, stream>>>(deg, invdeg, N);
    k_fill<<<eb, 256, 0, stream>>>(esrc, edst, row_ptr, cursor, srcs, E);

    // ---- graph starts ----
    k_gstart_init<<<(NG + 256) / 256, 256, 0, stream>>>(gstart, N, NG);
    k_gstart_mark<<<(N + 255) / 256, 256, 0, stream>>>(batch, gstart, N);
    k_gstart_fix<<<1, 64, 0, stream>>>(gstart, N, NG);

    // ---- layer 1 (fp32 math, bf16 out) ----
    int ab = (N + 3) / 4;
    k_agg11<<<ab, 256, 0, stream>>>(x, row_ptr, srcs, invdeg, agg11, N);
    k_layer1<<<N, 256, 0, stream>>>(x, agg11, Wl[0], bl[0], Wr[0], hA16, N);
    k_pool<<<dim3(NG, 8), 256, 0, stream>>>(hA16, gstart, gsum, 0, h8A);

    // ---- layers 2..5 (fp8 gather + bf16 MFMA) ----
    unsigned short* hc = hA16; unsigned short* hn = hB16;
    unsigned char*  f8c = h8A; unsigned char*  f8n = h8B;
    int gb = (N + 63) / 64;
    for (int L = 1; L < 5; ++L){
        k_agg200<<<ab, 256, 0, stream>>>(f8c, row_ptr, srcs, invdeg, agg16, N);
        const unsigned short* Wlp = wpack + (size_t)((L-1)*2 + 0) * PACK_ELEMS;
        const unsigned short* Wrp = wpack + (size_t)((L-1)*2 + 1) * PACK_ELEMS;
        k_sage_mfma<<<gb, 256, 0, stream>>>(agg16, hc, Wlp, Wrp,
                                            biasp + (L-1) * ROWP, hn, N);
        k_pool<<<dim3(NG, 8), 256, 0, stream>>>(hn, gstart, gsum, 200 * L, f8n);
        unsigned short* t = hc; hc = hn; hn = t;
        unsigned char*  t8 = f8c; f8c = f8n; f8n = t8;
    }

    // ---- pool finalize + MLP head ----
    k_pool_finalize<<<NG, 256, 0, stream>>>(gsum, gstart, NG);
    k_mlp<<<NG, 256, 0, stream>>>(gsum, pw1, pb1, t1, 1000, 500);
    k_mlp<<<NG, 256, 0, stream>>>(t1, pw2, pb2, t2, 500, 250);
    k_mlp3<<<1, 256, 0, stream>>>(t2, pw3, pb3, out, NG);
}

// Round 4
// 1850.590 us; speedup vs baseline: 2.1591x; 1.0577x over previous
//
#include <hip/hip_runtime.h>
#include <math.h>

typedef __attribute__((ext_vector_type(8))) short bf16x8;
typedef __attribute__((ext_vector_type(4))) float floatx4;
typedef __attribute__((ext_vector_type(2))) float floatx2;

#define ROWP 224          // padded row length (elements) for h/agg bf16 buffers
#define NT 14             // 14 x 16 = 224 output cols (200 real + pad)
#define KS 7              // 7 x 32 = 224 K (200 real + pad)
#define PACK_ELEMS (NT*KS*64*8)   // elements per packed weight matrix

__device__ __forceinline__ unsigned short f2bf(float f){
    union { float f; unsigned u; } v; v.f = f;
    unsigned r = v.u + 0x7FFF + ((v.u >> 16) & 1);
    return (unsigned short)(r >> 16);
}
__device__ __forceinline__ float bf2f(unsigned short u){
    union { unsigned u; float f; } v; v.u = ((unsigned)u) << 16;
    return v.f;
}

// ============================ CSR build ============================

__global__ void k_hist(const int* __restrict__ dst, int* __restrict__ deg, int E){
    int i = blockIdx.x * blockDim.x + threadIdx.x;
    if (i < E) atomicAdd(&deg[dst[i]], 1);
}

__global__ void k_scan_sums(const int* __restrict__ deg, int* __restrict__ csum, int N){
    __shared__ int sd[256];
    int base = blockIdx.x * 1024;
    int s = 0;
    for (int i = threadIdx.x; i < 1024; i += 256){
        int idx = base + i;
        s += (idx < N) ? deg[idx] : 0;
    }
    sd[threadIdx.x] = s; __syncthreads();
    for (int off = 128; off > 0; off >>= 1){
        if (threadIdx.x < off) sd[threadIdx.x] += sd[threadIdx.x + off];
        __syncthreads();
    }
    if (threadIdx.x == 0) csum[blockIdx.x] = sd[0];
}

__global__ void k_scan_top(int* __restrict__ csum, int n){
    if (blockIdx.x == 0 && threadIdx.x == 0){
        int run = 0;
        for (int i = 0; i < n; ++i){ int v = csum[i]; csum[i] = run; run += v; }
    }
}

__global__ void k_scan_apply(const int* __restrict__ deg, const int* __restrict__ csum,
                             int* __restrict__ row_ptr, int N, int E){
    __shared__ int ts[256];
    int base = blockIdx.x * 1024 + threadIdx.x * 4;
    int v[4]; int s = 0;
    #pragma unroll
    for (int j = 0; j < 4; ++j){
        int idx = base + j;
        v[j] = (idx < N) ? deg[idx] : 0;
        s += v[j];
    }
    ts[threadIdx.x] = s; __syncthreads();
    #pragma unroll
    for (int off = 1; off < 256; off <<= 1){
        int t = (threadIdx.x >= off) ? ts[threadIdx.x - off] : 0;
        __syncthreads();
        ts[threadIdx.x] += t;
        __syncthreads();
    }
    int excl = ts[threadIdx.x] - s + csum[blockIdx.x];
    #pragma unroll
    for (int j = 0; j < 4; ++j){
        int idx = base + j;
        if (idx < N) row_ptr[idx] = excl;
        excl += v[j];
    }
    if (blockIdx.x == 0 && threadIdx.x == 0) row_ptr[N] = E;
}

__global__ void k_inv_deg(const int* __restrict__ deg, float* __restrict__ inv_deg, int N){
    int i = blockIdx.x * blockDim.x + threadIdx.x;
    if (i < N) inv_deg[i] = 1.0f / fmaxf((float)deg[i], 1.0f);
}

__global__ void k_fill(const int* __restrict__ src, const int* __restrict__ dst,
                       const int* __restrict__ row_ptr, int* __restrict__ cursor,
                       int* __restrict__ srcs, int E){
    int i = blockIdx.x * blockDim.x + threadIdx.x;
    if (i < E){
        int d = dst[i];
        int pos = row_ptr[d] + atomicAdd(&cursor[d], 1);
        srcs[pos] = src[i];
    }
}

// ============================ graph segment starts ============================

__global__ void k_gstart_init(int* __restrict__ gstart, int N, int NG){
    int g = blockIdx.x * blockDim.x + threadIdx.x;
    if (g <= NG) gstart[g] = N;
}

__global__ void k_gstart_mark(const int* __restrict__ batch, int* __restrict__ gstart, int N){
    int i = blockIdx.x * blockDim.x + threadIdx.x;
    if (i < N){
        int b = batch[i];
        if (i == 0 || batch[i-1] != b) atomicMin(&gstart[b], i);
    }
}

__global__ void k_gstart_fix(int* __restrict__ gstart, int N, int NG){
    if (blockIdx.x == 0 && threadIdx.x == 0){
        for (int g = NG - 1; g >= 0; --g)
            if (gstart[g] == N) gstart[g] = gstart[g+1];
    }
}

// ============================ weight / bias / x packing ============================

__global__ void k_pack_w(const float* W0, const float* W1, const float* W2, const float* W3,
                         const float* W4, const float* W5, const float* W6, const float* W7,
                         unsigned short* __restrict__ out){
    const float* Ws[8] = {W0,W1,W2,W3,W4,W5,W6,W7};
    const float* W = Ws[blockIdx.z];
    int lane = threadIdx.x;
    int n  = blockIdx.x * 16 + (lane & 15);
    int k0 = blockIdx.y * 32 + (lane >> 4) * 8;
    unsigned short v[8];
    #pragma unroll
    for (int j = 0; j < 8; ++j){
        int k = k0 + j;
        float f = (n < 200 && k < 200) ? W[n * 200 + k] : 0.f;
        v[j] = f2bf(f);
    }
    uint4 u;
    u.x = (unsigned)v[0] | ((unsigned)v[1] << 16);
    u.y = (unsigned)v[2] | ((unsigned)v[3] << 16);
    u.z = (unsigned)v[4] | ((unsigned)v[5] << 16);
    u.w = (unsigned)v[6] | ((unsigned)v[7] << 16);
    size_t off = ((((size_t)blockIdx.z * NT + blockIdx.x) * KS + blockIdx.y) * 64 + lane) * 8;
    *reinterpret_cast<uint4*>(out + off) = u;
}

__global__ void k_pack_b(const float* b0, const float* b1, const float* b2, const float* b3,
                         float* __restrict__ out){
    const float* bs[4] = {b0,b1,b2,b3};
    int l = blockIdx.x, c = threadIdx.x;
    if (c < ROWP) out[l * ROWP + c] = (c < 200) ? bs[l][c] : 0.f;
}

// pack x (N x 11 fp32) -> bf16 rows of 16 (32 B each), pad zero
__global__ void k_pack_x(const float* __restrict__ x, unsigned short* __restrict__ xp, int N){
    int i = blockIdx.x * blockDim.x + threadIdx.x;
    int node = i >> 4, c = i & 15;
    if (node < N) xp[i] = (c < 11) ? f2bf(x[(size_t)node * 11 + c]) : 0;
}

// ============================ aggregation ============================

// K=11 edge-parallel: half-wave (32 lanes) per node, one edge per lane.
// Each lane loads the full packed row (24 B: uint4 + uint2), butterfly-reduce.
__global__ __launch_bounds__(256) void k_agg11(
    const unsigned short* __restrict__ xp, const int* __restrict__ row_ptr,
    const int* __restrict__ srcs, const float* __restrict__ inv_deg,
    float* __restrict__ agg, int N)
{
    int half = threadIdx.x >> 5;              // 0..7
    int node = blockIdx.x * 8 + half;
    int l = threadIdx.x & 31;
    if (node >= N) return;
    int beg = row_ptr[node], end = row_ptr[node + 1];

    float acc[12];
    #pragma unroll
    for (int i = 0; i < 12; ++i) acc[i] = 0.f;

    const uint4* x4 = reinterpret_cast<const uint4*>(xp);
    const uint2* x2 = reinterpret_cast<const uint2*>(xp);
    for (int e = beg + l; e < end; e += 32){
        int sn = srcs[e];
        uint4 a = x4[(size_t)sn * 2];
        uint2 b = x2[(size_t)sn * 4 + 2];
        union { unsigned u; float f; } c;
        c.u = a.x << 16;         acc[0] += c.f;
        c.u = a.x & 0xffff0000u; acc[1] += c.f;
        c.u = a.y << 16;         acc[2] += c.f;
        c.u = a.y & 0xffff0000u; acc[3] += c.f;
        c.u = a.z << 16;         acc[4] += c.f;
        c.u = a.z & 0xffff0000u; acc[5] += c.f;
        c.u = a.w << 16;         acc[6] += c.f;
        c.u = a.w & 0xffff0000u; acc[7] += c.f;
        c.u = b.x << 16;         acc[8] += c.f;
        c.u = b.x & 0xffff0000u; acc[9] += c.f;
        c.u = b.y << 16;         acc[10] += c.f;
        c.u = b.y & 0xffff0000u; acc[11] += c.f;
    }

    #pragma unroll
    for (int i = 0; i < 11; ++i){
        acc[i] += __shfl_xor(acc[i], 1, 64);
        acc[i] += __shfl_xor(acc[i], 2, 64);
        acc[i] += __shfl_xor(acc[i], 4, 64);
        acc[i] += __shfl_xor(acc[i], 8, 64);
        acc[i] += __shfl_xor(acc[i], 16, 64);
    }

    if (l == 0){
        float id = inv_deg[node];
        #pragma unroll
        for (int i = 0; i < 11; ++i)
            agg[(size_t)node * 11 + i] = acc[i] * id;
    }
}

// fp8 gather-aggregate (layers 2..5). One wave per dst node.
__device__ __forceinline__ void accum_fp8(float* acc, uint4 u){
    floatx2 f;
    f = __builtin_amdgcn_cvt_pk_f32_fp8((int)u.x, false); acc[0] += f[0];  acc[1] += f[1];
    f = __builtin_amdgcn_cvt_pk_f32_fp8((int)u.x, true ); acc[2] += f[0];  acc[3] += f[1];
    f = __builtin_amdgcn_cvt_pk_f32_fp8((int)u.y, false); acc[4] += f[0];  acc[5] += f[1];
    f = __builtin_amdgcn_cvt_pk_f32_fp8((int)u.y, true ); acc[6] += f[0];  acc[7] += f[1];
    f = __builtin_amdgcn_cvt_pk_f32_fp8((int)u.z, false); acc[8] += f[0];  acc[9] += f[1];
    f = __builtin_amdgcn_cvt_pk_f32_fp8((int)u.z, true ); acc[10] += f[0]; acc[11] += f[1];
    f = __builtin_amdgcn_cvt_pk_f32_fp8((int)u.w, false); acc[12] += f[0]; acc[13] += f[1];
    f = __builtin_amdgcn_cvt_pk_f32_fp8((int)u.w, true ); acc[14] += f[0]; acc[15] += f[1];
}

__global__ __launch_bounds__(256) void k_agg200(
    const unsigned char* __restrict__ h8, const int* __restrict__ row_ptr,
    const int* __restrict__ srcs, const float* __restrict__ inv_deg,
    unsigned short* __restrict__ agg, int N)
{
    int node = blockIdx.x * 4 + (threadIdx.x >> 6);
    int lane = threadIdx.x & 63;
    if (node >= N) return;
    int g = lane >> 4;    // group 0..3
    int l = lane & 15;    // lane-in-group; active if l < 14
    int beg = row_ptr[node], end = row_ptr[node + 1];

    float acc[16];
    #pragma unroll
    for (int i = 0; i < 16; ++i) acc[i] = 0.f;

    if (l < 14){
        const uint4* h4 = reinterpret_cast<const uint4*>(h8);
        int e = beg + g;
        for (; e + 4 < end; e += 8){
            int sa = srcs[e];
            int sb = srcs[e + 4];
            uint4 ua = h4[(size_t)sa * 14 + l];
            uint4 ub = h4[(size_t)sb * 14 + l];
            accum_fp8(acc, ua);
            accum_fp8(acc, ub);
        }
        if (e < end){
            int sa = srcs[e];
            uint4 ua = h4[(size_t)sa * 14 + l];
            accum_fp8(acc, ua);
        }
    }

    #pragma unroll
    for (int i = 0; i < 16; ++i){
        acc[i] += __shfl_xor(acc[i], 32, 64);
        acc[i] += __shfl_xor(acc[i], 16, 64);
    }

    if (g == 0 && l < 14){
        float id = inv_deg[node];
        unsigned d[8];
        #pragma unroll
        for (int i = 0; i < 8; ++i){
            d[i] = (unsigned)f2bf(acc[2*i] * id) | ((unsigned)f2bf(acc[2*i+1] * id) << 16);
        }
        uint4* a4 = reinterpret_cast<uint4*>(agg);
        size_t base = (size_t)node * 28 + (size_t)l * 2;
        uint4 o0; o0.x = d[0]; o0.y = d[1]; o0.z = d[2]; o0.w = d[3];
        uint4 o1; o1.x = d[4]; o1.y = d[5]; o1.z = d[6]; o1.w = d[7];
        a4[base] = o0;
        a4[base + 1] = o1;
    }
}

// ============================ layer 1 (K=11, fp32 math, bf16 out) ============================

__global__ __launch_bounds__(256) void k_layer1(
    const float* __restrict__ x, const float* __restrict__ aggx,
    const float* __restrict__ Wl, const float* __restrict__ bl, const float* __restrict__ Wr,
    unsigned short* __restrict__ outp, int N)
{
    __shared__ float xr[11];
    __shared__ float ar[11];
    int m = blockIdx.x;
    if (threadIdx.x < 11){
        xr[threadIdx.x] = x[(size_t)m * 11 + threadIdx.x];
        ar[threadIdx.x] = aggx[(size_t)m * 11 + threadIdx.x];
    }
    __syncthreads();
    int c = threadIdx.x;
    if (c < 200){
        float s = bl[c];
        #pragma unroll
        for (int k = 0; k < 11; ++k){
            s = fmaf(ar[k], Wl[c * 11 + k], s);
            s = fmaf(xr[k], Wr[c * 11 + k], s);
        }
        outp[(size_t)m * ROWP + c] = f2bf(fmaxf(s, 0.f));
    } else if (c < ROWP){
        outp[(size_t)m * ROWP + c] = 0;
    }
}

// ============================ MFMA SAGE GEMM (layers 2..5) ============================

__global__ __launch_bounds__(256) void k_sage_mfma(
    const unsigned short* __restrict__ Aagg, const unsigned short* __restrict__ Ah,
    const unsigned short* __restrict__ Wlp, const unsigned short* __restrict__ Wrp,
    const float* __restrict__ biasp, unsigned short* __restrict__ outp, int M)
{
    const int wave = threadIdx.x >> 6;
    const int lane = threadIdx.x & 63;
    const int n = lane & 15;
    const int q = lane >> 4;
    int row = blockIdx.x * 64 + wave * 16 + n;
    int rowc = row < M ? row : (M - 1);

    floatx4 acc[NT];
    #pragma unroll
    for (int nt = 0; nt < NT; ++nt) acc[nt] = (floatx4){0.f, 0.f, 0.f, 0.f};

    #pragma unroll
    for (int phase = 0; phase < 2; ++phase){
        const unsigned short* A = phase ? Ah : Aagg;
        const unsigned short* Wp = phase ? Wrp : Wlp;
        const unsigned short* arow = A + (size_t)rowc * ROWP + q * 8;
        #pragma unroll
        for (int ks = 0; ks < KS; ++ks){
            bf16x8 a = *reinterpret_cast<const bf16x8*>(arow + ks * 32);
            #pragma unroll
            for (int nt = 0; nt < NT; ++nt){
                bf16x8 b = *reinterpret_cast<const bf16x8*>(Wp + ((size_t)(nt * KS + ks) * 64 + lane) * 8);
                acc[nt] = __builtin_amdgcn_mfma_f32_16x16x32_bf16(a, b, acc[nt], 0, 0, 0);
            }
        }
    }

    int r0 = blockIdx.x * 64 + wave * 16 + q * 4;
    #pragma unroll
    for (int nt = 0; nt < NT; ++nt){
        float bsv = biasp[nt * 16 + n];
        #pragma unroll
        for (int r = 0; r < 4; ++r){
            int rr = r0 + r;
            if (rr < M){
                float v = fmaxf(acc[nt][r] + bsv, 0.f);
                outp[(size_t)rr * ROWP + nt * 16 + n] = f2bf(v);
            }
        }
    }
}

// ============================ pooling + fp8 shadow write ============================
// Grid (NG, 8) x 256 threads = 32 row-partitions per graph (4 waves x 8 blocks.y).
// Each thread owns 4 consecutive columns: uint2 bf16 load, packed uint fp8 store.

__global__ __launch_bounds__(256) void k_pool(
    const unsigned short* __restrict__ h, const int* __restrict__ gstart,
    float* __restrict__ gsum, int col_off, unsigned char* __restrict__ h8)
{
    int g = blockIdx.x;
    int beg = gstart[g], end = gstart[g+1];
    int len = end - beg;
    if (len <= 0) return;
    int sub = threadIdx.x >> 6;                 // 0..3
    int t   = threadIdx.x & 63;                 // lane
    if (t >= 56) return;
    int pidx = blockIdx.y * 4 + sub;            // 0..31
    int chunk = (len + 31) >> 5;
    int rb = beg + pidx * chunk;
    int re = rb + chunk; if (re > end) re = end;
    if (rb >= re) return;
    int c0 = t * 4;

    float s0 = 0.f, s1 = 0.f, s2 = 0.f, s3 = 0.f;
    for (int r = rb; r < re; ++r){
        uint2 u = *reinterpret_cast<const uint2*>(h + (size_t)r * ROWP + c0);
        union { unsigned u; float f; } c;
        float v0, v1, v2, v3;
        c.u = u.x << 16;         v0 = c.f;
        c.u = u.x & 0xffff0000u; v1 = c.f;
        c.u = u.y << 16;         v2 = c.f;
        c.u = u.y & 0xffff0000u; v3 = c.f;
        s0 += v0; s1 += v1; s2 += v2; s3 += v3;
        int pk = __builtin_amdgcn_cvt_pk_fp8_f32(v0, v1, 0, false);
        pk = __builtin_amdgcn_cvt_pk_fp8_f32(v2, v3, pk, true);
        *reinterpret_cast<unsigned*>(h8 + (size_t)r * ROWP + c0) = (unsigned)pk;
    }
    if (c0 < 200){
        float* gs = &gsum[(size_t)g * 1000 + col_off + c0];
        atomicAdd(gs + 0, s0);
        atomicAdd(gs + 1, s1);
        atomicAdd(gs + 2, s2);
        atomicAdd(gs + 3, s3);
    }
}

__global__ __launch_bounds__(256) void k_pool_finalize(
    float* __restrict__ gsum, const int* __restrict__ gstart, int NG)
{
    int g = blockIdx.x;
    int cnt = gstart[g+1] - gstart[g];
    float inv = 1.0f / fmaxf((float)cnt, 1.0f);
    for (int i = threadIdx.x; i < 1000; i += 256)
        gsum[(size_t)g * 1000 + i] *= inv;
}

// ============================ MLP head (fp32) ============================

__global__ __launch_bounds__(256) void k_mlp(
    const float* __restrict__ in, const float* __restrict__ W,
    const float* __restrict__ b, float* __restrict__ outp, int Fin, int Fout)
{
    __shared__ __align__(16) float row[1000];
    int g = blockIdx.x;
    for (int i = threadIdx.x; i < Fin; i += 256) row[i] = in[(size_t)g * Fin + i];
    __syncthreads();
    int f4 = Fin >> 2;
    for (int c = threadIdx.x; c < Fout; c += 256){
        const float4* w4 = reinterpret_cast<const float4*>(W + (size_t)c * Fin);
        const float4* r4 = reinterpret_cast<const float4*>(row);
        float s = b[c];
        for (int k = 0; k < f4; ++k){
            float4 wv = w4[k]; float4 rv = r4[k];
            s = fmaf(wv.x, rv.x, s);
            s = fmaf(wv.y, rv.y, s);
            s = fmaf(wv.z, rv.z, s);
            s = fmaf(wv.w, rv.w, s);
        }
        outp[(size_t)g * Fout + c] = s;
    }
}

__global__ void k_mlp3(const float* __restrict__ in, const float* __restrict__ W,
                       const float* __restrict__ b, float* __restrict__ outp, int NG)
{
    int g = blockIdx.x * blockDim.x + threadIdx.x;
    if (g < NG){
        float s = b[0];
        const float* r = in + (size_t)g * 250;
        for (int k = 0; k < 250; ++k) s = fmaf(r[k], W[k], s);
        outp[g] = 1.0f / (1.0f + expf(-s));
    }
}

// ============================ launch ============================

extern "C" void kernel_launch(void* const* d_in, const int* in_sizes, int n_in,
                              void* d_out, int out_size, void* d_ws, size_t ws_size,
                              hipStream_t stream)
{
    const float* x    = (const float*)d_in[0];
    const int*   ei   = (const int*)d_in[1];
    const int*   batch= (const int*)d_in[2];
    const float* Wl[5]; const float* bl[5]; const float* Wr[5];
    for (int i = 0; i < 5; ++i){
        Wl[i] = (const float*)d_in[3 + 3*i];
        bl[i] = (const float*)d_in[4 + 3*i];
        Wr[i] = (const float*)d_in[5 + 3*i];
    }
    const float* pw1 = (const float*)d_in[18]; const float* pb1 = (const float*)d_in[19];
    const float* pw2 = (const float*)d_in[20]; const float* pb2 = (const float*)d_in[21];
    const float* pw3 = (const float*)d_in[22]; const float* pb3 = (const float*)d_in[23];
    float* out = (float*)d_out;

    const int N  = in_sizes[2];
    const int E  = in_sizes[1] / 2;
    const int NG = out_size;
    const int* esrc = ei;
    const int* edst = ei + E;

    // ---- workspace carve ----
    char* p = (char*)d_ws;
    auto carve = [&](size_t bytes)->void* {
        void* r = (void*)p;
        p += (bytes + 255) & ~(size_t)255;
        return r;
    };
    int*   deg     = (int*)  carve((size_t)N * 4);
    int*   cursor  = (int*)  carve((size_t)N * 4);
    int*   row_ptr = (int*)  carve(((size_t)N + 1) * 4);
    int*   csum    = (int*)  carve(4096);
    float* invdeg  = (float*)carve((size_t)N * 4);
    int*   gstart  = (int*)  carve(((size_t)NG + 1) * 4);
    int*   srcs    = (int*)  carve((size_t)E * 4);
    float* agg11   = (float*)carve((size_t)N * 11 * 4);
    unsigned short* xp    = (unsigned short*)carve((size_t)N * 16 * 2);
    unsigned short* agg16 = (unsigned short*)carve((size_t)N * ROWP * 2);
    unsigned short* hA16  = (unsigned short*)carve((size_t)N * ROWP * 2);
    unsigned short* hB16  = (unsigned short*)carve((size_t)N * ROWP * 2);
    unsigned char*  h8A   = (unsigned char*) carve((size_t)N * ROWP);
    unsigned char*  h8B   = (unsigned char*) carve((size_t)N * ROWP);
    unsigned short* wpack = (unsigned short*)carve((size_t)8 * PACK_ELEMS * 2);
    float* biasp   = (float*)carve((size_t)4 * ROWP * 4);
    float* gsum    = (float*)carve((size_t)NG * 1000 * 4);
    float* t1      = (float*)carve((size_t)NG * 500 * 4);
    float* t2      = (float*)carve((size_t)NG * 250 * 4);

    // ---- zero what must be zero ----
    hipMemsetAsync(deg,    0, (size_t)N * 4, stream);
    hipMemsetAsync(cursor, 0, (size_t)N * 4, stream);
    hipMemsetAsync(gsum,   0, (size_t)NG * 1000 * 4, stream);

    // ---- packing ----
    k_pack_w<<<dim3(NT, KS, 8), 64, 0, stream>>>(
        Wl[1], Wr[1], Wl[2], Wr[2], Wl[3], Wr[3], Wl[4], Wr[4], wpack);
    k_pack_b<<<4, ROWP, 0, stream>>>(bl[1], bl[2], bl[3], bl[4], biasp);
    k_pack_x<<<(N * 16 + 255) / 256, 256, 0, stream>>>(x, xp, N);

    // ---- CSR build ----
    int eb = (E + 255) / 256;
    k_hist<<<eb, 256, 0, stream>>>(edst, deg, E);
    int nchunks = (N + 1023) / 1024;
    k_scan_sums<<<nchunks, 256, 0, stream>>>(deg, csum, N);
    k_scan_top<<<1, 64, 0, stream>>>(csum, nchunks);
    k_scan_apply<<<nchunks, 256, 0, stream>>>(deg, csum, row_ptr, N, E);
    k_inv_deg<<<(N + 255) / 256, 256, 0, stream>>>(deg, invdeg, N);
    k_fill<<<eb, 256, 0, stream>>>(esrc, edst, row_ptr, cursor, srcs, E);

    // ---- graph starts ----
    k_gstart_init<<<(NG + 256) / 256, 256, 0, stream>>>(gstart, N, NG);
    k_gstart_mark<<<(N + 255) / 256, 256, 0, stream>>>(batch, gstart, N);
    k_gstart_fix<<<1, 64, 0, stream>>>(gstart, N, NG);

    // ---- layer 1 (fp32 math, bf16 out) ----
    k_agg11<<<(N + 7) / 8, 256, 0, stream>>>(xp, row_ptr, srcs, invdeg, agg11, N);
    k_layer1<<<N, 256, 0, stream>>>(x, agg11, Wl[0], bl[0], Wr[0], hA16, N);
    k_pool<<<dim3(NG, 8), 256, 0, stream>>>(hA16, gstart, gsum, 0, h8A);

    // ---- layers 2..5 (fp8 gather + bf16 MFMA) ----
    unsigned short* hc = hA16; unsigned short* hn = hB16;
    unsigned char*  f8c = h8A; unsigned char*  f8n = h8B;
    int ab = (N + 3) / 4;
    int gb = (N + 63) / 64;
    for (int L = 1; L < 5; ++L){
        k_agg200<<<ab, 256, 0, stream>>>(f8c, row_ptr, srcs, invdeg, agg16, N);
        const unsigned short* Wlp = wpack + (size_t)((L-1)*2 + 0) * PACK_ELEMS;
        const unsigned short* Wrp = wpack + (size_t)((L-1)*2 + 1) * PACK_ELEMS;
        k_sage_mfma<<<gb, 256, 0, stream>>>(agg16, hc, Wlp, Wrp,
                                            biasp + (L-1) * ROWP, hn, N);
        k_pool<<<dim3(NG, 8), 256, 0, stream>>>(hn, gstart, gsum, 200 * L, f8n);
        unsigned short* t = hc; hc = hn; hn = t;
        unsigned char*  t8 = f8c; f8c = f8n; f8n = t8;
    }

    // ---- pool finalize + MLP head ----
    k_pool_finalize<<<NG, 256, 0, stream>>>(gsum, gstart, NG);
    k_mlp<<<NG, 256, 0, stream>>>(gsum, pw1, pb1, t1, 1000, 500);
    k_mlp<<<NG, 256, 0, stream>>>(t1, pw2, pb2, t2, 500, 250);
    k_mlp3<<<1, 256, 0, stream>>>(t2, pw3, pb3, out, NG);
}